// Round 1
// baseline (1950.394 us; speedup 1.0000x reference)
//
#include <hip/hip_runtime.h>
#include <hip/hip_fp16.h>

// TGCN 2-layer, T=12, F=8, H=64, N=50k, E=800k.
// R13 = R12 + forced memory-level parallelism in all gather phases.
// Theory: VGPR_Count=32/20 proves the compiler re-rolled the batch-of-8 load
// loops (occupancy-targeted regalloc), leaving ~4-6 outstanding misses/wave;
// all gathers sit at the latency-bound ~0.46 lines/cy/CU rate with VALU 24%,
// HBM 22%, Mfma 0 (nothing saturated). Fix: __launch_bounds__(,8) (cap 64
// VGPR, occupancy unchanged at 2 blocks/CU) + explicit scalar-register load
// batches + dual-pair interleaved batches for the u32 gathers (16 lines in
// flight/wave). Accumulation order per output unchanged -> bitwise identical
// (absmax expected 0.01757812).

#define FT 96
#define TSTEPS 12

typedef _Float16 f16x8 __attribute__((ext_vector_type(8)));
typedef float f32x4 __attribute__((ext_vector_type(4)));

static __device__ __forceinline__ float lo2f(unsigned v) {
    __half2 h2 = *reinterpret_cast<const __half2*>(&v);
    return __low2float(h2);
}
static __device__ __forceinline__ float hi2f(unsigned v) {
    __half2 h2 = *reinterpret_cast<const __half2*>(&v);
    return __high2float(h2);
}
static __device__ __forceinline__ float wof(unsigned p) {
    return __half2float(__ushort_as_half((unsigned short)(p >> 16)));
}

// ---------------- CSR build ----------------
__global__ void hist_k(const int* __restrict__ dst, int* __restrict__ deg, int E) {
    int e = blockIdx.x * blockDim.x + threadIdx.x;
    if (e < E) atomicAdd(&deg[dst[e]], 1);
}

__global__ __launch_bounds__(256) void partial_k(const int* __restrict__ deg,
                                                 int* __restrict__ part, int N) {
    __shared__ int sm[256];
    int i = blockIdx.x * 256 + threadIdx.x;
    sm[threadIdx.x] = (i < N) ? deg[i] : 0;
    __syncthreads();
    for (int off = 128; off > 0; off >>= 1) {
        if (threadIdx.x < off) sm[threadIdx.x] += sm[threadIdx.x + off];
        __syncthreads();
    }
    if (threadIdx.x == 0) part[blockIdx.x] = sm[0];
}

__global__ __launch_bounds__(256) void scanpart_k(int* __restrict__ part,
                                                  int* __restrict__ rowptr,
                                                  int G, int N) {
    __shared__ int sm[256];
    int v = (threadIdx.x < G) ? part[threadIdx.x] : 0;
    sm[threadIdx.x] = v;
    __syncthreads();
    for (int off = 1; off < 256; off <<= 1) {
        int t = (threadIdx.x >= (unsigned)off) ? sm[threadIdx.x - off] : 0;
        __syncthreads();
        sm[threadIdx.x] += t;
        __syncthreads();
    }
    if (threadIdx.x < G) part[threadIdx.x] = sm[threadIdx.x] - v;
    if (threadIdx.x == 255) rowptr[N] = sm[255];
}

__global__ __launch_bounds__(256) void scanchunk_k(const int* __restrict__ deg,
                                                   const int* __restrict__ part,
                                                   int* __restrict__ rowptr,
                                                   int* __restrict__ cursor, int N) {
    __shared__ int sm[256];
    int i = blockIdx.x * 256 + threadIdx.x;
    int v = (i < N) ? deg[i] : 0;
    sm[threadIdx.x] = v;
    __syncthreads();
    for (int off = 1; off < 256; off <<= 1) {
        int t = (threadIdx.x >= (unsigned)off) ? sm[threadIdx.x - off] : 0;
        __syncthreads();
        sm[threadIdx.x] += t;
        __syncthreads();
    }
    int excl = sm[threadIdx.x] - v + part[blockIdx.x];
    if (i < N) { rowptr[i] = excl; cursor[i] = excl; }
}

__global__ void fill_k(const int* __restrict__ src, const int* __restrict__ dst,
                       const float* __restrict__ ew, int* __restrict__ cursor,
                       unsigned* __restrict__ csr_ew, int E) {
    int e = blockIdx.x * blockDim.x + threadIdx.x;
    if (e >= E) return;
    int pos = atomicAdd(&cursor[dst[e]], 1);
    unsigned hw = (unsigned)__half_as_ushort(__float2half(ew[e]));
    csr_ew[pos] = (unsigned)src[e] | (hw << 16);
}

__global__ void x2h_k(const float* __restrict__ x, _Float16* __restrict__ xh, int M) {
    int i = blockIdx.x * blockDim.x + threadIdx.x;
    if (i < M) xh[i] = (_Float16)x[i];
}

// weight prep: fp16 transposed [C][K] layouts
__global__ void wprep_k(const float* __restrict__ Wg0, const float* __restrict__ Wc0,
                        const float* __restrict__ Wg1, const float* __restrict__ Wc1,
                        _Float16* __restrict__ Wg1t, _Float16* __restrict__ Wc1t,
                        _Float16* __restrict__ Wc0t, _Float16* __restrict__ Wg0t_h,
                        _Float16* __restrict__ Wg0t_x) {
    int i = blockIdx.x * 256 + threadIdx.x;
    if (i < 128 * 128) { int c = i >> 7, k = i & 127; Wg1t[i] = (_Float16)Wg1[k * 128 + c]; }
    if (i < 64 * 128)  { int c = i >> 7, k = i & 127; Wc1t[i] = (_Float16)Wc1[k * 64 + c]; }
    if (i < 64 * 96)   { int c = i / 96, k = i - c * 96;
                         Wc0t[i] = (k < 72) ? (_Float16)Wc0[k * 64 + c] : (_Float16)0.f; }
    if (i < 128 * 64)  { int c = i >> 6, k = i & 63; Wg0t_h[i] = (_Float16)Wg0[(8 + k) * 128 + c]; }
    if (i < 128 * 32)  { int c = i >> 5, k = i & 31;
                         Wg0t_x[i] = (k < 8) ? (_Float16)Wg0[k * 128 + c] : (_Float16)0.f; }
}

// gather of xh (96 fp16 ch/node), writes transposed aggXt[t][n][f]
// R13: forced 8-wide load batches (explicit scalars), 32-bit row indexing.
__global__ __launch_bounds__(256, 8) void gather96_k(
    const _Float16* __restrict__ xh, const int* __restrict__ rowptr,
    const unsigned* __restrict__ csr_ew, float* __restrict__ aggXt, int N) {
    int n = blockIdx.x * 4 + (threadIdx.x >> 6);
    if (n >= N) return;
    int c = threadIdx.x & 63;
    int beg = rowptr[n], end = rowptr[n + 1];
    int deg = end - beg;
    float a0 = 0.f, a1 = 0.f;
    unsigned ev = 0;
    if (c < deg) ev = csr_ew[beg + c];
    int m = deg < 64 ? deg : 64;
    int m8 = (m + 7) & ~7;
    for (int j = 0; j < m8; j += 8) {
        float x0, x1, x2, x3, x4, x5, x6, x7;
        float y0, y1, y2, y3, y4, y5, y6, y7;
        float w0, w1, w2, w3, w4, w5, w6, w7;
#define GX(k) { unsigned p = __shfl(ev, j + k); w##k = wof(p); \
                unsigned o = (p & 0xffffu) * 96u + (unsigned)c; \
                x##k = (float)xh[o]; \
                y##k = (c < 32) ? (float)xh[o + 64] : 0.f; }
        GX(0) GX(1) GX(2) GX(3) GX(4) GX(5) GX(6) GX(7)
#undef GX
#define FX(k) { a0 = fmaf(w##k, x##k, a0); a1 = fmaf(w##k, y##k, a1); }
        FX(0) FX(1) FX(2) FX(3) FX(4) FX(5) FX(6) FX(7)
#undef FX
    }
    for (int e = beg + 64; e < end; ++e) {
        unsigned p = csr_ew[e];
        float w = wof(p);
        unsigned o = (p & 0xffffu) * 96u + (unsigned)c;
        a0 = fmaf(w, (float)xh[o], a0);
        if (c < 32) a1 = fmaf(w, (float)xh[o + 64], a1);
    }
    { int f = c / 12, tt = c - f * 12;
      aggXt[((size_t)tt * N + n) * 8 + f] = a0; }
    if (c < 32) { int cc = 64 + c; int f = cc / 12, tt = cc - f * 12;
      aggXt[((size_t)tt * N + n) * 8 + f] = a1; }
}

// t=0 gate0 (h0=0): only z0 needed (r0*h0 = 0)
__global__ void g0z_k(const float* __restrict__ aggXt, const float* __restrict__ Wg0,
                      const float* __restrict__ bg0, _Float16* __restrict__ Zh, int N) {
    int i = blockIdx.x * blockDim.x + threadIdx.x;
    int n = i >> 6;
    if (n >= N) return;
    int c = i & 63;
    float acc = bg0[64 + c];
#pragma unroll
    for (int f = 0; f < 8; ++f) acc += aggXt[(size_t)n * 8 + f] * Wg0[f * 128 + 64 + c];
    Zh[(size_t)n * 64 + c] = (_Float16)(1.f / (1.f + __expf(-acc)));
}

// R13 dual-pair gather: both of a wave's pairs interleaved -> 16 random lines
// in flight per wave. beg/deg are per-lane (half-resolved), jm wave-uniform.
// Per-output accumulation order identical to R12 (bitwise-same results).
static __device__ __forceinline__ void gpair_dual32(
    const unsigned* __restrict__ feat32, const unsigned* __restrict__ csr_ew,
    int beg0, int deg0, int jm0, int beg1, int deg1, int jm1,
    int c2, int base,
    float& o00, float& o01, float& o10, float& o11) {
    const int m0 = deg0 < 32 ? deg0 : 32;
    const int m1 = deg1 < 32 ? deg1 : 32;
    unsigned ev0 = 0, ev1 = 0;
    if (c2 < m0) ev0 = csr_ew[beg0 + c2];
    if (c2 < m1) ev1 = csr_ew[beg1 + c2];
    float a00 = 0.f, a01 = 0.f, a10 = 0.f, a11 = 0.f;
    const int jmax = jm0 > jm1 ? jm0 : jm1;
    for (int j = 0; j < jmax; j += 8) {
        const bool d0 = (j < jm0), d1 = (j < jm1);   // wave-uniform
        unsigned v00, v01, v02, v03, v04, v05, v06, v07;
        unsigned v10, v11, v12, v13, v14, v15, v16, v17;
        float w00, w01, w02, w03, w04, w05, w06, w07;
        float w10, w11, w12, w13, w14, w15, w16, w17;
        if (d0) {
#define GA(k) { unsigned p = __shfl(ev0, base + j + k); w0##k = wof(p); \
                v0##k = feat32[((p & 0xffffu) << 5) + (unsigned)c2]; }
            GA(0) GA(1) GA(2) GA(3) GA(4) GA(5) GA(6) GA(7)
#undef GA
        }
        if (d1) {
#define GB(k) { unsigned p = __shfl(ev1, base + j + k); w1##k = wof(p); \
                v1##k = feat32[((p & 0xffffu) << 5) + (unsigned)c2]; }
            GB(0) GB(1) GB(2) GB(3) GB(4) GB(5) GB(6) GB(7)
#undef GB
        }
        if (d0) {
#define FA(k) { a00 = fmaf(w0##k, lo2f(v0##k), a00); a01 = fmaf(w0##k, hi2f(v0##k), a01); }
            FA(0) FA(1) FA(2) FA(3) FA(4) FA(5) FA(6) FA(7)
#undef FA
        }
        if (d1) {
#define FB(k) { a10 = fmaf(w1##k, lo2f(v1##k), a10); a11 = fmaf(w1##k, hi2f(v1##k), a11); }
            FB(0) FB(1) FB(2) FB(3) FB(4) FB(5) FB(6) FB(7)
#undef FB
        }
    }
    int end0 = beg0 + deg0;
    for (int e = beg0 + 32; e < end0; ++e) {
        unsigned p = csr_ew[e];
        float w = wof(p);
        unsigned v = feat32[((p & 0xffffu) << 5) + (unsigned)c2];
        a00 = fmaf(w, lo2f(v), a00);
        a01 = fmaf(w, hi2f(v), a01);
    }
    int end1 = beg1 + deg1;
    for (int e = beg1 + 32; e < end1; ++e) {
        unsigned p = csr_ew[e];
        float w = wof(p);
        unsigned v = feat32[((p & 0xffffu) << 5) + (unsigned)c2];
        a10 = fmaf(w, lo2f(v), a10);
        a11 = fmaf(w, hi2f(v), a11);
    }
    o00 = a00; o01 = a01; o10 = a10; o11 = a11;
}

// ---------------- layer-0 cand (1024 thr, MFMA dense) ----------------
// A-tile sA[64][104] fp16: k0-7 aggX, k8-71 gconv(RH0), k72-95 zero.
__global__ __launch_bounds__(1024, 8) void l0_cand(
    const _Float16* __restrict__ RH0h, const float* __restrict__ aggXt, int t,
    const int* __restrict__ rowptr, const unsigned* __restrict__ csr_ew,
    const _Float16* __restrict__ Wc0t, const float* __restrict__ bc,
    const _Float16* __restrict__ Zh, float* __restrict__ h0f,
    unsigned* __restrict__ h01, int N) {
    __shared__ _Float16 sA[64 * 104];
    const int tid = threadIdx.x;
    const int lane = tid & 63;
    const int wid = __builtin_amdgcn_readfirstlane(tid >> 6);   // 0..15
    const int nb = blockIdx.x * 64;
    // zero pad cols 72..103 + aggX fill cols 0..7 (first 512 threads)
    if (tid < 512) {
        int nl = tid >> 3, k0 = 72 + ((tid & 7) << 2);
#pragma unroll
        for (int q = 0; q < 4; ++q) sA[nl * 104 + k0 + q] = (_Float16)0.f;
        int f = tid & 7, n = nb + nl;
        sA[nl * 104 + f] = (n < N) ? (_Float16)aggXt[((size_t)t * N + n) * 8 + f] : (_Float16)0.f;
    }
    // dual-pair gather cols 8..71
    {
        const int pr0 = wid * 2;
        const int n0 = nb + pr0 * 2;
        const int n1 = n0 + 2;
        int begA0 = 0, degA0 = 0, begB0 = 0, degB0 = 0;
        int begA1 = 0, degA1 = 0, begB1 = 0, degB1 = 0;
        if (n0 < N)     { begA0 = rowptr[n0];     degA0 = rowptr[n0 + 1] - begA0; }
        if (n0 + 1 < N) { begB0 = rowptr[n0 + 1]; degB0 = rowptr[n0 + 2] - begB0; }
        if (n1 < N)     { begA1 = rowptr[n1];     degA1 = rowptr[n1 + 1] - begA1; }
        if (n1 + 1 < N) { begB1 = rowptr[n1 + 1]; degB1 = rowptr[n1 + 2] - begB1; }
        const int half = lane >> 5, c2 = lane & 31, base = half << 5;
        int dm0 = degA0 > degB0 ? degA0 : degB0;
        int dm1 = degA1 > degB1 ? degA1 : degB1;
        int jm0 = dm0 < 32 ? dm0 : 32; jm0 = (jm0 + 7) & ~7;
        int jm1 = dm1 < 32 ? dm1 : 32; jm1 = (jm1 + 7) & ~7;
        float o00, o01, o10, o11;
        gpair_dual32((const unsigned*)RH0h, csr_ew,
                     half ? begB0 : begA0, half ? degB0 : degA0, jm0,
                     half ? begB1 : begA1, half ? degB1 : degA1, jm1,
                     c2, base, o00, o01, o10, o11);
        const int nl0 = pr0 * 2 + half;
        const int nl1 = nl0 + 2;
        sA[nl0 * 104 + 8 + 2 * c2]     = (_Float16)o00;
        sA[nl0 * 104 + 8 + 2 * c2 + 1] = (_Float16)o01;
        sA[nl1 * 104 + 8 + 2 * c2]     = (_Float16)o10;
        sA[nl1 * 104 + 8 + 2 * c2 + 1] = (_Float16)o11;
    }
    __syncthreads();
    // dense: out[64][64] = sA @ Wc0t^T (K=96), tanh; 1 tile per wave (4x4 tiles)
    const int ln15 = lane & 15, quad = lane >> 4;
    const int mt = wid & 3, nc = wid >> 2;      // mt 0..3, nc 0..3
    const int mrow = mt * 16 + ln15;
    const int col = nc * 16 + ln15;
    f16x8 afr[3];
#pragma unroll
    for (int kc = 0; kc < 3; ++kc)
        afr[kc] = *(const f16x8*)&sA[mrow * 104 + kc * 32 + quad * 8];
    float b = bc[col];
    f32x4 acc = {b, b, b, b};
#pragma unroll
    for (int kc = 0; kc < 3; ++kc) {
        f16x8 bfr = *(const f16x8*)&Wc0t[(size_t)col * 96 + kc * 32 + quad * 8];
        acc = __builtin_amdgcn_mfma_f32_16x16x32_f16(afr[kc], bfr, acc, 0, 0, 0);
    }
    __syncthreads();
    // stage c into sA cols 0..63
#pragma unroll
    for (int r = 0; r < 4; ++r) {
        float e = __expf(2.f * acc[r]);
        float c = 1.f - 2.f / (e + 1.f);
        int row = mt * 16 + quad * 4 + r;
        sA[row * 104 + col] = (_Float16)c;
    }
    __syncthreads();
    for (int i = tid; i < 4096; i += 1024) {
        int nl = i >> 6, cc = i & 63, n = nb + nl;
        if (n < N) {
            size_t idx = (size_t)n * 64 + cc;
            float z = (float)Zh[idx];
            float hv = h0f[idx];
            float nh = z * hv + (1.f - z) * (float)sA[nl * 104 + cc];
            h0f[idx] = nh;
            reinterpret_cast<__half*>(h01)[idx * 2] = __float2half(nh);
        }
    }
}

// ---------------- layer-1 gate (1024 thr, dual gather + MFMA) ---------------
// A-tile sA[64][136]: k0-63 gconv(h0'), k64-127 gconv(h1)
__global__ __launch_bounds__(1024, 8) void l1_gate(
    const unsigned* __restrict__ h01, const float* __restrict__ h1f,
    const int* __restrict__ rowptr, const unsigned* __restrict__ csr_ew,
    const _Float16* __restrict__ Wg1t, const float* __restrict__ bg,
    unsigned* __restrict__ Aglobh32, _Float16* __restrict__ Zh,
    _Float16* __restrict__ RH1h, int N) {
    __shared__ _Float16 sA[64 * 136];
    const int tid = threadIdx.x;
    const int lane = tid & 63;
    const int wid = __builtin_amdgcn_readfirstlane(tid >> 6);   // 0..15
    const int nb = blockIdx.x * 64;
    const uint2* __restrict__ f2 = (const uint2*)h01;
    for (int i = 0; i < 2; ++i) {
        int pr = wid * 2 + i;
        int nlA = pr * 2, nlB = nlA + 1;
        int nA = nb + nlA, nB = nb + nlB;
        int begA = 0, degA = 0, begB = 0, degB = 0;
        if (nA < N) { begA = rowptr[nA]; degA = rowptr[nA + 1] - begA; }
        if (nB < N) { begB = rowptr[nB]; degB = rowptr[nB + 1] - begB; }
        const int half = lane >> 5, c2 = lane & 31;
        const int beg = half ? begB : begA;
        const int deg = half ? degB : degA;
        const int m = deg < 32 ? deg : 32;
        unsigned ev = 0;
        if (c2 < m) ev = csr_ew[beg + c2];
        int dmax = degA > degB ? degA : degB;
        int jm = dmax < 32 ? dmax : 32;
        jm = (jm + 7) & ~7;
        float p00 = 0.f, p01 = 0.f, p10 = 0.f, p11 = 0.f;
        const int base = half << 5;
        for (int j = 0; j < jm; j += 8) {
            uint2 v0, v1, v2, v3, v4, v5, v6, v7;
            float w0, w1, w2, w3, w4, w5, w6, w7;
#define LG(k) { unsigned p = __shfl(ev, base + j + k); w##k = wof(p); \
                v##k = f2[((p & 0xffffu) << 5) + (unsigned)c2]; }
            LG(0) LG(1) LG(2) LG(3) LG(4) LG(5) LG(6) LG(7)
#undef LG
#define FG(k) { p00 = fmaf(w##k, lo2f(v##k.x), p00); p10 = fmaf(w##k, hi2f(v##k.x), p10); \
                p01 = fmaf(w##k, lo2f(v##k.y), p01); p11 = fmaf(w##k, hi2f(v##k.y), p11); }
            FG(0) FG(1) FG(2) FG(3) FG(4) FG(5) FG(6) FG(7)
#undef FG
        }
        int end = beg + deg;
        for (int e = beg + 32; e < end; ++e) {
            unsigned p = csr_ew[e];
            float w = wof(p);
            uint2 v = f2[((p & 0xffffu) << 5) + (unsigned)c2];
            p00 = fmaf(w, lo2f(v.x), p00);
            p10 = fmaf(w, hi2f(v.x), p10);
            p01 = fmaf(w, lo2f(v.y), p01);
            p11 = fmaf(w, hi2f(v.y), p11);
        }
        int nl = (lane < 32) ? nlA : nlB;
        int c2w = lane & 31;
        sA[nl * 136 + 2 * c2w] = (_Float16)p00;
        sA[nl * 136 + 2 * c2w + 1] = (_Float16)p01;
        sA[nl * 136 + 64 + 2 * c2w] = (_Float16)p10;
        sA[nl * 136 + 64 + 2 * c2w + 1] = (_Float16)p11;
    }
    __syncthreads();
    // Aglob dump (fp16, packed u32 view) — reads sA cols 0..63
    for (int i = tid; i < 2048; i += 1024) {
        int nl = i >> 5, c2 = i & 31, n = nb + nl;
        if (n < N) Aglobh32[(size_t)n * 32 + c2] = ((const unsigned*)sA)[nl * 68 + c2];
    }
    // dense: rz[64][128] = sA @ Wg1t^T (K=128), sigmoid; 2 tiles per wave
    const int ln15 = lane & 15, quad = lane >> 4;
    const int mt = wid & 3, ng = wid >> 2;       // ng 0..3, 2 N-tiles each
    const int mrow = mt * 16 + ln15;
    f16x8 afr[4];
#pragma unroll
    for (int kc = 0; kc < 4; ++kc)
        afr[kc] = *(const f16x8*)&sA[mrow * 136 + kc * 32 + quad * 8];
    f32x4 acc[2];
    int cols[2];
#pragma unroll
    for (int nt = 0; nt < 2; ++nt) {
        int col = (ng * 2 + nt) * 16 + ln15;
        cols[nt] = col;
        float b = bg[col];
        f32x4 a = {b, b, b, b};
#pragma unroll
        for (int kc = 0; kc < 4; ++kc) {
            f16x8 bfr = *(const f16x8*)&Wg1t[(size_t)col * 128 + kc * 32 + quad * 8];
            a = __builtin_amdgcn_mfma_f32_16x16x32_f16(afr[kc], bfr, a, 0, 0, 0);
        }
        acc[nt] = a;
    }
    __syncthreads();
    // stage r (cols 0-63) and z (cols 64-127) into sA
#pragma unroll
    for (int nt = 0; nt < 2; ++nt) {
#pragma unroll
        for (int r = 0; r < 4; ++r) {
            float s = 1.f / (1.f + __expf(-acc[nt][r]));
            int row = mt * 16 + quad * 4 + r;
            sA[row * 136 + cols[nt]] = (_Float16)s;
        }
    }
    __syncthreads();
    for (int i = tid; i < 4096; i += 1024) {
        int nl = i >> 6, cc = i & 63, n = nb + nl;
        if (n < N) {
            size_t idx = (size_t)n * 64 + cc;
            float r = (float)sA[nl * 136 + cc];
            float z = (float)sA[nl * 136 + 64 + cc];
            RH1h[idx] = (_Float16)(r * h1f[idx]);
            Zh[idx] = (_Float16)z;
        }
    }
}

// ---------------- layer-1 cand + fused gate0(t+1) (1024 thr, MFMA) ---------
// sA[64][136]: k0-63 = Aglobh (gconv h0'), k64-127 = gconv(RH1).
// sX[64][40]: k0-7 aggX(t+1), rest 0.
__global__ __launch_bounds__(1024, 8) void l1_cand_fused(
    const _Float16* __restrict__ RH1h, const unsigned* __restrict__ Aglobh32,
    const float* __restrict__ aggXt, int tn, int do_gate, int final,
    const int* __restrict__ rowptr, const unsigned* __restrict__ csr_ew,
    const _Float16* __restrict__ Wc1t, const float* __restrict__ bc1,
    const _Float16* __restrict__ Wg0t_h, const _Float16* __restrict__ Wg0t_x,
    const float* __restrict__ bg0, const float* __restrict__ h0f,
    _Float16* __restrict__ Zh, _Float16* __restrict__ RH0h,
    float* __restrict__ h1f, unsigned* __restrict__ h01,
    const float* __restrict__ Wout, const float* __restrict__ bout,
    float* __restrict__ out, int N) {
    __shared__ _Float16 sA[64 * 136];
    __shared__ _Float16 sX[64 * 40];
    const int tid = threadIdx.x;
    const int lane = tid & 63;
    const int wid = __builtin_amdgcn_readfirstlane(tid >> 6);   // 0..15
    const int nb = blockIdx.x * 64;
    // sX zero (cols 8..39) + aggX fill (cols 0..7) — first 512 threads
    if (tid < 512) {
        int nl = tid >> 3, k0 = 8 + ((tid & 7) << 2);
#pragma unroll
        for (int q = 0; q < 4; ++q) sX[nl * 40 + k0 + q] = (_Float16)0.f;
        if (do_gate) {
            int f = tid & 7, n = nb + nl;
            sX[nl * 40 + f] = (n < N) ? (_Float16)aggXt[((size_t)tn * N + n) * 8 + f] : (_Float16)0.f;
        }
    }
    // Aglobh -> sA cols 0..63 (u32 packed)
    for (int i = tid; i < 2048; i += 1024) {
        int nl = i >> 5, c2 = i & 31, n = nb + nl;
        ((unsigned*)sA)[nl * 68 + c2] = (n < N) ? Aglobh32[(size_t)n * 32 + c2] : 0u;
    }
    // dual-pair gather gconv(RH1) -> sA cols 64..127
    {
        const int pr0 = wid * 2;
        const int n0 = nb + pr0 * 2;
        const int n1 = n0 + 2;
        int begA0 = 0, degA0 = 0, begB0 = 0, degB0 = 0;
        int begA1 = 0, degA1 = 0, begB1 = 0, degB1 = 0;
        if (n0 < N)     { begA0 = rowptr[n0];     degA0 = rowptr[n0 + 1] - begA0; }
        if (n0 + 1 < N) { begB0 = rowptr[n0 + 1]; degB0 = rowptr[n0 + 2] - begB0; }
        if (n1 < N)     { begA1 = rowptr[n1];     degA1 = rowptr[n1 + 1] - begA1; }
        if (n1 + 1 < N) { begB1 = rowptr[n1 + 1]; degB1 = rowptr[n1 + 2] - begB1; }
        const int half = lane >> 5, c2 = lane & 31, base = half << 5;
        int dm0 = degA0 > degB0 ? degA0 : degB0;
        int dm1 = degA1 > degB1 ? degA1 : degB1;
        int jm0 = dm0 < 32 ? dm0 : 32; jm0 = (jm0 + 7) & ~7;
        int jm1 = dm1 < 32 ? dm1 : 32; jm1 = (jm1 + 7) & ~7;
        float o00, o01, o10, o11;
        gpair_dual32((const unsigned*)RH1h, csr_ew,
                     half ? begB0 : begA0, half ? degB0 : degA0, jm0,
                     half ? begB1 : begA1, half ? degB1 : degA1, jm1,
                     c2, base, o00, o01, o10, o11);
        const int nl0 = pr0 * 2 + half;
        const int nl1 = nl0 + 2;
        sA[nl0 * 136 + 64 + 2 * c2]     = (_Float16)o00;
        sA[nl0 * 136 + 64 + 2 * c2 + 1] = (_Float16)o01;
        sA[nl1 * 136 + 64 + 2 * c2]     = (_Float16)o10;
        sA[nl1 * 136 + 64 + 2 * c2 + 1] = (_Float16)o11;
    }
    __syncthreads();
    const int ln15 = lane & 15, quad = lane >> 4;
    const int mt = wid & 3, ng = wid >> 2;      // ng 0..3
    const int mrow = mt * 16 + ln15;
    f16x8 afr[4];
#pragma unroll
    for (int kc = 0; kc < 4; ++kc)
        afr[kc] = *(const f16x8*)&sA[mrow * 136 + kc * 32 + quad * 8];
    // cand: c1[64][64] = sA @ Wc1t^T (K=128), 1 tile per wave
    const int colc = ng * 16 + ln15;
    f32x4 accc;
    {
        float b = bc1[colc];
        f32x4 a = {b, b, b, b};
#pragma unroll
        for (int kc = 0; kc < 4; ++kc) {
            f16x8 bfr = *(const f16x8*)&Wc1t[(size_t)colc * 128 + kc * 32 + quad * 8];
            a = __builtin_amdgcn_mfma_f32_16x16x32_f16(afr[kc], bfr, a, 0, 0, 0);
        }
        accc = a;
    }
    // gate0(t+1): rz0[64][128] = sX@Wg0t_x + sA(0:64)@Wg0t_h, 2 tiles/wave
    f32x4 accg[2];
    int colg[2];
    if (do_gate) {
        f16x8 xfr = *(const f16x8*)&sX[mrow * 40 + quad * 8];
#pragma unroll
        for (int nt = 0; nt < 2; ++nt) {
            int col = (ng * 2 + nt) * 16 + ln15;
            colg[nt] = col;
            float b = bg0[col];
            f32x4 a = {b, b, b, b};
            f16x8 bx = *(const f16x8*)&Wg0t_x[(size_t)col * 32 + quad * 8];
            a = __builtin_amdgcn_mfma_f32_16x16x32_f16(xfr, bx, a, 0, 0, 0);
#pragma unroll
            for (int kc = 0; kc < 2; ++kc) {
                f16x8 bfr = *(const f16x8*)&Wg0t_h[(size_t)col * 64 + kc * 32 + quad * 8];
                a = __builtin_amdgcn_mfma_f32_16x16x32_f16(afr[kc], bfr, a, 0, 0, 0);
            }
            accg[nt] = a;
        }
    }
    __syncthreads();
    // stage: c1 -> sA cols 64..127; r0 -> sA cols 0..63 (z0 stays in regs)
#pragma unroll
    for (int r = 0; r < 4; ++r) {
        float e = __expf(2.f * accc[r]);
        float c = 1.f - 2.f / (e + 1.f);
        int row = mt * 16 + quad * 4 + r;
        sA[row * 136 + 64 + colc] = (_Float16)c;
    }
    if (do_gate) {
#pragma unroll
        for (int nt = 0; nt < 2; ++nt) {
            if (colg[nt] < 64) {
#pragma unroll
                for (int r = 0; r < 4; ++r) {
                    float s = 1.f / (1.f + __expf(-accg[nt][r]));
                    int row = mt * 16 + quad * 4 + r;
                    sA[row * 136 + colg[nt]] = (_Float16)s;
                }
            }
        }
    }
    __syncthreads();
    // epilogue-1: h1 update (+RH0h, +final out)
    for (int i = tid; i < 4096; i += 1024) {
        int nl = i >> 6, cc = i & 63, n = nb + nl;
        float nh = 0.f;
        if (n < N) {
            size_t idx = (size_t)n * 64 + cc;
            float z1 = (float)Zh[idx];
            float hv = h1f[idx];
            nh = z1 * hv + (1.f - z1) * (float)sA[nl * 136 + 64 + cc];
            if (!final) {
                h1f[idx] = nh;
                reinterpret_cast<__half*>(h01)[idx * 2 + 1] = __float2half(nh);
            }
            if (do_gate) RH0h[idx] = (_Float16)((float)sA[nl * 136 + cc] * h0f[idx]);
        }
        if (final) {
            float p = nh * Wout[cc];
            for (int off = 32; off > 0; off >>= 1) p += __shfl_down(p, off);
            if (cc == 0 && n < N) out[n] = p + bout[0];
        }
    }
    if (do_gate) {
        __syncthreads();
        // stage z0 (gate cols >= 64) -> sA cols 0..63
#pragma unroll
        for (int nt = 0; nt < 2; ++nt) {
            if (colg[nt] >= 64) {
#pragma unroll
                for (int r = 0; r < 4; ++r) {
                    float s = 1.f / (1.f + __expf(-accg[nt][r]));
                    int row = mt * 16 + quad * 4 + r;
                    sA[row * 136 + (colg[nt] - 64)] = (_Float16)s;
                }
            }
        }
        __syncthreads();
        for (int i = tid; i < 4096; i += 1024) {
            int nl = i >> 6, cc = i & 63, n = nb + nl;
            if (n < N) Zh[(size_t)n * 64 + cc] = sA[nl * 136 + cc];
        }
    }
}

static inline size_t align16(size_t v) { return (v + 15) & ~(size_t)15; }

extern "C" void kernel_launch(void* const* d_in, const int* in_sizes, int n_in,
                              void* d_out, int out_size, void* d_ws, size_t ws_size,
                              hipStream_t stream) {
    const float* x   = (const float*)d_in[0];
    const int*   ei  = (const int*)d_in[1];
    const float* ew  = (const float*)d_in[2];
    const float* Wg0 = (const float*)d_in[3];
    const float* bg0 = (const float*)d_in[4];
    const float* Wc0 = (const float*)d_in[5];
    const float* bc0 = (const float*)d_in[6];
    const float* Wg1 = (const float*)d_in[7];
    const float* bg1 = (const float*)d_in[8];
    const float* Wc1 = (const float*)d_in[9];
    const float* bc1 = (const float*)d_in[10];
    const float* Wout = (const float*)d_in[11];
    const float* bout = (const float*)d_in[12];

    const int N = in_sizes[0] / FT;
    const int E = in_sizes[2];
    const int* src = ei;
    const int* dst = ei + E;

    char* base = (char*)d_ws;
    size_t off = 0;
    int* deg = (int*)(base + off);            off = align16(off + (size_t)N * 4);
    int* cursor = (int*)(base + off);         off = align16(off + (size_t)N * 4);
    int* rowptr = (int*)(base + off);         off = align16(off + (size_t)(N + 1) * 4);
    int* part = (int*)(base + off);           off = align16(off + 256 * 4);
    unsigned* csr_ew = (unsigned*)(base + off);  off = align16(off + (size_t)E * 4);
    float* aggXt = (float*)(base + off);      off = align16(off + (size_t)N * FT * 4);
    float* h0f = (float*)(base + off);        off = align16(off + (size_t)N * 64 * 4);
    float* h1f = (float*)(base + off);        off = align16(off + (size_t)N * 64 * 4);
    unsigned* h01 = (unsigned*)(base + off);  off = align16(off + (size_t)N * 64 * 4);
    unsigned* Aglobh32 = (unsigned*)(base + off); off = align16(off + (size_t)N * 32 * 4);
    _Float16* Zh = (_Float16*)(base + off);   off = align16(off + (size_t)N * 64 * 2);
    _Float16* RH0h = (_Float16*)(base + off); off = align16(off + (size_t)N * 64 * 2);
    _Float16* RH1h = (_Float16*)(base + off); off = align16(off + (size_t)N * 64 * 2);
    _Float16* xh = (_Float16*)(base + off);   off = align16(off + (size_t)N * FT * 2);
    _Float16* Wg1t = (_Float16*)(base + off); off = align16(off + 128 * 128 * 2);
    _Float16* Wc1t = (_Float16*)(base + off); off = align16(off + 64 * 128 * 2);
    _Float16* Wc0t = (_Float16*)(base + off); off = align16(off + 64 * 96 * 2);
    _Float16* Wg0t_h = (_Float16*)(base + off); off = align16(off + 128 * 64 * 2);
    _Float16* Wg0t_x = (_Float16*)(base + off); off = align16(off + 128 * 32 * 2);

    const int gE   = (E + 255) / 256;
    const int gN4  = (N + 3) / 4;
    const int gN64 = (N + 63) / 64;
    const int G    = (N + 255) / 256;

    hipMemsetAsync(deg, 0, (size_t)N * 4, stream);
    hipMemsetAsync(h0f, 0, (size_t)N * 64 * 4, stream);
    hipMemsetAsync(h1f, 0, (size_t)N * 64 * 4, stream);
    hipMemsetAsync(h01, 0, (size_t)N * 64 * 4, stream);
    hipMemsetAsync(RH0h, 0, (size_t)N * 64 * 2, stream);

    x2h_k<<<(N * FT + 255) / 256, 256, 0, stream>>>(x, xh, N * FT);
    wprep_k<<<64, 256, 0, stream>>>(Wg0, Wc0, Wg1, Wc1, Wg1t, Wc1t, Wc0t, Wg0t_h, Wg0t_x);
    hist_k<<<gE, 256, 0, stream>>>(dst, deg, E);
    partial_k<<<G, 256, 0, stream>>>(deg, part, N);
    scanpart_k<<<1, 256, 0, stream>>>(part, rowptr, G, N);
    scanchunk_k<<<G, 256, 0, stream>>>(deg, part, rowptr, cursor, N);
    fill_k<<<gE, 256, 0, stream>>>(src, dst, ew, cursor, csr_ew, E);
    gather96_k<<<gN4, 256, 0, stream>>>(xh, rowptr, csr_ew, aggXt, N);

    // t=0: h0=0 -> RH0h=0 (memset); z0 from aggX only
    g0z_k<<<(N * 64 + 255) / 256, 256, 0, stream>>>(aggXt, Wg0, bg0, Zh, N);

    for (int t = 0; t < TSTEPS; ++t) {
        l0_cand<<<gN64, 1024, 0, stream>>>(RH0h, aggXt, t, rowptr, csr_ew,
                                           Wc0t, bc0, Zh, h0f, h01, N);
        l1_gate<<<gN64, 1024, 0, stream>>>(h01, h1f, rowptr, csr_ew,
                                           Wg1t, bg1, Aglobh32, Zh, RH1h, N);
        l1_cand_fused<<<gN64, 1024, 0, stream>>>(RH1h, Aglobh32, aggXt, t + 1,
                                                 (t + 1 < TSTEPS) ? 1 : 0,
                                                 (t + 1 == TSTEPS) ? 1 : 0,
                                                 rowptr, csr_ew,
                                                 Wc1t, bc1, Wg0t_h, Wg0t_x, bg0,
                                                 h0f, Zh, RH0h, h1f, h01,
                                                 Wout, bout, (float*)d_out, N);
    }
}